// Round 18
// baseline (1502.213 us; speedup 1.0000x reference)
//
#include <hip/hip_runtime.h>
#include <hip/hip_bf16.h>
#include <stdint.h>

// InvBlock: out = concat(u_new, v_new)
//   v_mid = tanh(u_old @ W1^T + b1); v_new = v_old + 0.1 * (v_mid @ W1)
//   u_mid = tanh(v_new @ W0^T + b0); u_new = u_old - 0.1 * (u_mid @ W0)
// R18: V7 = V3 interior with BK=128 (128 KiB LDS single-buf — free, since
// occupancy is register-pinned at 1 block/CU per R12). Halves sync ops per
// unit K (2 VMW + 4 BAR + 2 LGK0 per 128-K vs V3's 4+8+4); 64-MFMA
// clusters; same registers (frags reused across k-halves).
// A/B: t1,vnew = V7; t2,unew = V3 controls.

typedef __attribute__((ext_vector_type(8))) short short8;   // 8 bf16 = 4 VGPRs
typedef __attribute__((ext_vector_type(4))) float f32x4;

#define DEVINL __device__ __forceinline__

DEVINL ushort f2b(float f) {  // fp32 -> bf16 bits, RNE
  union { float f; uint32_t u; } v; v.f = f;
  uint32_t u = v.u;
  return (ushort)((u + 0x7fffu + ((u >> 16) & 1u)) >> 16);
}

DEVINL float fast_tanh(float x) {
  x = fminf(10.0f, fmaxf(-10.0f, x));
  float e = __expf(2.0f * x);
  return (e - 1.0f) * __builtin_amdgcn_rcpf(e + 1.0f);
}

DEVINL void gload16(const ushort* g, ushort* l) {
  __builtin_amdgcn_global_load_lds(
      (const __attribute__((address_space(1))) void*)g,
      (__attribute__((address_space(3))) void*)l, 16, 0, 0);
}

template<int MH, int NH>
DEVINL void mfma_quad(f32x4 (&acc)[8][4], const short8 (&a)[4][2],
                      const short8 (&b)[2][2]) {
#pragma unroll
  for (int ks = 0; ks < 2; ++ks)
#pragma unroll
    for (int mi = 0; mi < 4; ++mi)
#pragma unroll
      for (int ni = 0; ni < 2; ++ni)
        acc[MH * 4 + mi][NH * 2 + ni] = __builtin_amdgcn_mfma_f32_16x16x32_bf16(
            a[mi][ks], b[ni][ks], acc[MH * 4 + mi][NH * 2 + ni], 0, 0, 0);
}

// A: M x K bf16 row-major.  Bt: N x K bf16 row-major.
// MODE 0: Tout = bf16(tanh(acc + bias[n]))
// MODE 1: o = xres + step*acc -> outres fp32 + vbout bf16
// MODE 2: same as 1, no vbout
// SCHED 3: V3 single-buf 64 KiB BK=64, counted vmcnt(2/6), 2-phase.
// SCHED 7: V7 single-buf 128 KiB BK=128, counted vmcnt(8), k-half phases.
template<int MODE, int SCHED>
DEVINL void gemm_body(const ushort* __restrict__ A, const ushort* __restrict__ Bt,
                      const float* __restrict__ bias, ushort* __restrict__ Tout,
                      const float* __restrict__ xres, float* __restrict__ outres,
                      ushort* __restrict__ vbout, float step, int M, int N, int K)
{
  constexpr int LDS_N = (SCHED == 7) ? 65536 : 32768;
  __shared__ __align__(16) ushort ldsU[LDS_N];

  const int tid  = threadIdx.x;
  const int wave = tid >> 6, lane = tid & 63;
  const int wr = wave >> 2, wc = wave & 3;       // 2 x 4 wave grid
  const int lr = lane & 15, hi = lane >> 4;

  // T1: XCD-aware block swizzle (nwg % 8 == 0 for all our shapes)
  const int GX = gridDim.x;
  const int nwg = GX * gridDim.y;
  const int lin = blockIdx.y * GX + blockIdx.x;
  const int swz = (lin & 7) * (nwg >> 3) + (lin >> 3);
  const int by = swz / GX, bx = swz - by * GX;
  const int m0 = by * 256, n0 = bx * 256;

  // ---- staging source offsets (inverse-swizzled global source, rule #21)
  const int kb_st = ((tid & 7) * 16) ^ (((tid >> 3) & 7) << 4);
  int offA[2][2], offB[2][2];   // [half][j], constant-indexed only
#pragma unroll
  for (int j = 0; j < 2; ++j) {
    const int rp = j * 64 + (tid >> 3);
#pragma unroll
    for (int h = 0; h < 2; ++h) {
      offA[h][j] = (m0 + (rp >> 6) * 128 + h * 64 + (rp & 63)) * K + (kb_st >> 1);
      offB[h][j] = (n0 + (rp >> 5) * 64 + h * 32 + (rp & 31)) * K + (kb_st >> 1);
    }
  }

  // ---- V3 staging (64-K tiles, A at 0, B at 16384 elements)
#define STAGE_A3(half, t) do {                                                 \
    gload16(A + (size_t)offA[half][0] + (size_t)(t) * 64,                      \
            ldsU + (half) * 8192 + tid * 8);                                   \
    gload16(A + (size_t)offA[half][1] + (size_t)(t) * 64,                      \
            ldsU + (half) * 8192 + 4096 + tid * 8);                            \
  } while (0)
#define STAGE_B3(half, t) do {                                                 \
    gload16(Bt + (size_t)offB[half][0] + (size_t)(t) * 64,                     \
            ldsU + 16384 + (half) * 8192 + tid * 8);                           \
    gload16(Bt + (size_t)offB[half][1] + (size_t)(t) * 64,                     \
            ldsU + 16384 + (half) * 8192 + 4096 + tid * 8);                    \
  } while (0)

  // ---- V7 staging (128-K tiles; regions: A_kh at kh*16384, B_kh at
  //      32768 + kh*16384; within-region layout identical to V3)
#define STAGE_A7(kh, half, t) do {                                             \
    gload16(A + (size_t)offA[half][0] + (size_t)(t) * 128 + (kh) * 64,         \
            ldsU + (kh) * 16384 + (half) * 8192 + tid * 8);                    \
    gload16(A + (size_t)offA[half][1] + (size_t)(t) * 128 + (kh) * 64,         \
            ldsU + (kh) * 16384 + (half) * 8192 + 4096 + tid * 8);             \
  } while (0)
#define STAGE_B7(kh, half, t) do {                                             \
    gload16(Bt + (size_t)offB[half][0] + (size_t)(t) * 128 + (kh) * 64,        \
            ldsU + 32768 + (kh) * 16384 + (half) * 8192 + tid * 8);            \
    gload16(Bt + (size_t)offB[half][1] + (size_t)(t) * 128 + (kh) * 64,        \
            ldsU + 32768 + (kh) * 16384 + (half) * 8192 + 4096 + tid * 8);     \
  } while (0)
#define STAGE8_7(kh, t) do {                                                   \
    STAGE_A7(kh, 0, t); STAGE_A7(kh, 1, t);                                    \
    STAGE_B7(kh, 0, t); STAGE_B7(kh, 1, t);                                    \
  } while (0)

  // ---- fragment-read element offsets (ushort units; row&7 == lane&7)
  const int xm = (lane & 7) << 4;
  const int kbr0 = (hi * 16) ^ xm;          // bytes
  const int kbr1 = (64 + hi * 16) ^ xm;
  const int eA0 = (wr * 64 + lr) * 64 + (kbr0 >> 1);
  const int eA1 = (wr * 64 + lr) * 64 + (kbr1 >> 1);
  const int eB0 = (wc * 32 + lr) * 64 + (kbr0 >> 1);
  const int eB1 = (wc * 32 + lr) * 64 + (kbr1 >> 1);

#define LDSE(idx) (*(const short8*)&ldsU[idx])
#define READ_A8(dst, base, half) do {                                          \
    dst[0][0] = LDSE((base) + (half)*8192 +    0 + eA0);                       \
    dst[0][1] = LDSE((base) + (half)*8192 +    0 + eA1);                       \
    dst[1][0] = LDSE((base) + (half)*8192 + 1024 + eA0);                       \
    dst[1][1] = LDSE((base) + (half)*8192 + 1024 + eA1);                       \
    dst[2][0] = LDSE((base) + (half)*8192 + 2048 + eA0);                       \
    dst[2][1] = LDSE((base) + (half)*8192 + 2048 + eA1);                       \
    dst[3][0] = LDSE((base) + (half)*8192 + 3072 + eA0);                       \
    dst[3][1] = LDSE((base) + (half)*8192 + 3072 + eA1);                       \
  } while (0)
#define READ_B4(dst, base, half) do {                                          \
    dst[0][0] = LDSE((base) + (half)*8192 +    0 + eB0);                       \
    dst[0][1] = LDSE((base) + (half)*8192 +    0 + eB1);                       \
    dst[1][0] = LDSE((base) + (half)*8192 + 1024 + eB0);                       \
    dst[1][1] = LDSE((base) + (half)*8192 + 1024 + eB1);                       \
  } while (0)

  f32x4 acc[8][4] = {};
  short8 a0[4][2], a1[4][2], b0[2][2], b1[2][2];

#define VMW(n) asm volatile("s_waitcnt vmcnt(" #n ")" ::: "memory")
#define LGK0 asm volatile("s_waitcnt lgkmcnt(0)" ::: "memory")
#define SCB __builtin_amdgcn_sched_barrier(0)
#define BAR __builtin_amdgcn_s_barrier()
#define PRIO1 __builtin_amdgcn_s_setprio(1)
#define PRIO0 __builtin_amdgcn_s_setprio(0)

  if constexpr (SCHED == 7) {
    // ======== V7: BK=128 single-buf, k-half phases ========
    // Phase (kh): VMW(8) [drains this kh's 8 loads; other kh's 8 stay in
    // flight]; BAR [block-wide resident]; 24 reads; LGK0; BAR [all waves
    // done reading kh regions]; stage kh <- t+1; 64 MFMA.
    const int NT = K >> 7;
#define V7_PHASE(kh, STG, VN)                                                  \
    VMW(VN); BAR; SCB;                                                         \
    READ_A8(a0, (kh)*16384, 0); READ_B4(b0, 32768 + (kh)*16384, 0);            \
    READ_A8(a1, (kh)*16384, 1); READ_B4(b1, 32768 + (kh)*16384, 1);            \
    LGK0; SCB;                                                                 \
    BAR; SCB;                                                                  \
    STG;                                                                       \
    PRIO1;                                                                     \
    mfma_quad<0, 0>(acc, a0, b0); mfma_quad<1, 0>(acc, a1, b0);                \
    mfma_quad<0, 1>(acc, a0, b1); mfma_quad<1, 1>(acc, a1, b1);                \
    PRIO0;

    STAGE8_7(0, 0); STAGE8_7(1, 0);
#pragma unroll 1
    for (int t = 0; t < NT - 1; ++t) {
      V7_PHASE(0, STAGE8_7(0, t + 1), 8)
      V7_PHASE(1, STAGE8_7(1, t + 1), 8)
    }
    V7_PHASE(0, , 8)
    V7_PHASE(1, , 0)
#undef V7_PHASE
  } else {
    // ======== V3: BK=64 single-buf, counted vmcnt(2/6), 2-phase ========
    const int NT = K >> 6;
    STAGE_A3(0, 0); STAGE_A3(1, 0); STAGE_B3(0, 0);
    STAGE_B3(1, 0);
#pragma unroll 1
    for (int t = 0; t < NT - 1; ++t) {
      VMW(2); BAR; SCB;
      READ_A8(a0, 0, 0); READ_B4(b0, 16384, 0); READ_A8(a1, 0, 1);
      LGK0; SCB;
      BAR; SCB;
      STAGE_A3(0, t + 1); STAGE_A3(1, t + 1); STAGE_B3(0, t + 1);
      PRIO1;
      mfma_quad<0, 0>(acc, a0, b0); mfma_quad<1, 0>(acc, a1, b0);
      PRIO0;
      VMW(6); BAR; SCB;
      READ_B4(b1, 16384, 1);
      LGK0; SCB;
      BAR; SCB;
      STAGE_B3(1, t + 1);
      PRIO1;
      mfma_quad<0, 1>(acc, a0, b1); mfma_quad<1, 1>(acc, a1, b1);
      PRIO0;
    }
    VMW(2); BAR; SCB;
    READ_A8(a0, 0, 0); READ_B4(b0, 16384, 0); READ_A8(a1, 0, 1);
    LGK0; SCB;
    PRIO1;
    mfma_quad<0, 0>(acc, a0, b0); mfma_quad<1, 0>(acc, a1, b0);
    PRIO0;
    VMW(0); BAR; SCB;
    READ_B4(b1, 16384, 1);
    LGK0; SCB;
    PRIO1;
    mfma_quad<0, 1>(acc, a0, b1); mfma_quad<1, 1>(acc, a1, b1);
    PRIO0;
  }

  // ---- epilogue: C row = m0+wr*128+mi*16+hi*4+r, col = n0+wc*64+ni*16+lr
  const int mrow0 = m0 + wr * 128 + hi * 4;
  const int ncol0 = n0 + wc * 64 + lr;
#pragma unroll
  for (int mi = 0; mi < 8; ++mi) {
#pragma unroll
    for (int ni = 0; ni < 4; ++ni) {
      const int col = ncol0 + ni * 16;
      if (MODE == 0) {
        const float bv = bias[col];
#pragma unroll
        for (int r = 0; r < 4; ++r) {
          const int row = mrow0 + mi * 16 + r;
          Tout[(size_t)row * N + col] = f2b(fast_tanh(acc[mi][ni][r] + bv));
        }
      } else {
#pragma unroll
        for (int r = 0; r < 4; ++r) {
          const int row = mrow0 + mi * 16 + r;
          const size_t oi = (size_t)row * 4096 + col;
          const float v = fmaf(step, acc[mi][ni][r], xres[oi]);
          outres[oi] = v;
          if (MODE == 1) vbout[(size_t)row * N + col] = f2b(v);
        }
      }
    }
  }
#undef STAGE_A3
#undef STAGE_B3
#undef STAGE_A7
#undef STAGE_B7
#undef STAGE8_7
#undef LDSE
#undef READ_A8
#undef READ_B4
#undef VMW
#undef LGK0
#undef SCB
#undef BAR
#undef PRIO1
#undef PRIO0
}

// Distinct kernel names per dispatch for unambiguous rocprof attribution.
__global__ __launch_bounds__(512, 2)
void gemm_t1(const ushort* A, const ushort* Bt, const float* bias,
             ushort* Tout, int M, int N, int K) {
  gemm_body<0, 7>(A, Bt, bias, Tout, nullptr, nullptr, nullptr, 0.f, M, N, K);
}
__global__ __launch_bounds__(512, 2)
void gemm_vnew(const ushort* A, const ushort* Bt, const float* xres,
               float* outres, ushort* vbout, float step, int M, int N, int K) {
  gemm_body<1, 7>(A, Bt, nullptr, nullptr, xres, outres, vbout, step, M, N, K);
}
__global__ __launch_bounds__(512, 2)
void gemm_t2(const ushort* A, const ushort* Bt, const float* bias,
             ushort* Tout, int M, int N, int K) {
  gemm_body<0, 3>(A, Bt, bias, Tout, nullptr, nullptr, nullptr, 0.f, M, N, K);
}
__global__ __launch_bounds__(512, 2)
void gemm_unew(const ushort* A, const ushort* Bt, const float* xres,
               float* outres, float step, int M, int N, int K) {
  gemm_body<2, 3>(A, Bt, nullptr, nullptr, xres, outres, nullptr, step, M, N, K);
}

// u_b[m, 0:2048] = bf16(x[m, 0:2048])   (x has ld 4096); short8 stores
__global__ void cast_strided_half(const float* __restrict__ x,
                                  ushort* __restrict__ dst)
{
  const int i = blockIdx.x * blockDim.x + threadIdx.x;   // [0, 16384*256)
  const int row = i >> 8;
  const int c8  = (i & 255) * 8;
  const float4 v0 = *(const float4*)&x[(size_t)row * 4096 + c8];
  const float4 v1 = *(const float4*)&x[(size_t)row * 4096 + c8 + 4];
  short8 o;
  o[0] = (short)f2b(v0.x); o[1] = (short)f2b(v0.y);
  o[2] = (short)f2b(v0.z); o[3] = (short)f2b(v0.w);
  o[4] = (short)f2b(v1.x); o[5] = (short)f2b(v1.y);
  o[6] = (short)f2b(v1.z); o[7] = (short)f2b(v1.w);
  *(short8*)&dst[(size_t)row * 2048 + c8] = o;
}

// Both weights in one launch: W (4096x2048 fp32) -> Wb (bf16) + Wt (bf16^T)
__global__ void pack_both(const float* __restrict__ W0, const float* __restrict__ W1,
                          ushort* __restrict__ W0b, ushort* __restrict__ W0t,
                          ushort* __restrict__ W1b, ushort* __restrict__ W1t)
{
  const float* W = blockIdx.z ? W1 : W0;
  ushort* Wb = blockIdx.z ? W1b : W0b;
  ushort* Wt = blockIdx.z ? W1t : W0t;
  __shared__ float tile[32][33];
  const int bx = blockIdx.x * 32;
  const int by = blockIdx.y * 32;
  const int tx = threadIdx.x, ty = threadIdx.y;   // 32x8
#pragma unroll
  for (int j = ty; j < 32; j += 8) {
    const float v = W[(size_t)(by + j) * 2048 + bx + tx];
    tile[j][tx] = v;
    Wb[(size_t)(by + j) * 2048 + bx + tx] = f2b(v);
  }
  __syncthreads();
#pragma unroll
  for (int j = ty; j < 32; j += 8) {
    Wt[(size_t)(bx + j) * 4096 + by + tx] = f2b(tile[tx][j]);
  }
}

extern "C" void kernel_launch(void* const* d_in, const int* in_sizes, int n_in,
                              void* d_out, int out_size, void* d_ws, size_t ws_size,
                              hipStream_t stream)
{
  const float* x  = (const float*)d_in[0];   // 16384 x 4096
  const float* W0 = (const float*)d_in[1];   // 4096 x 2048
  const float* b0 = (const float*)d_in[2];
  const float* W1 = (const float*)d_in[3];
  const float* b1 = (const float*)d_in[4];
  float* out = (float*)d_out;                // 16384 x 4096

  const int Mrows = 16384, H2 = 4096, Hh = 2048;

  uint8_t* ws = (uint8_t*)d_ws;
  ushort* T   = (ushort*)ws;                                   // 128 MiB
  ushort* Ab  = (ushort*)(ws + (size_t)134217728);             //  64 MiB
  ushort* W0b = (ushort*)(ws + (size_t)134217728 + 67108864);
  ushort* W0t = W0b + 8388608;
  ushort* W1b = W0t + 8388608;
  ushort* W1t = W1b + 8388608;

  cast_strided_half<<<16384, 256, 0, stream>>>(x, Ab);
  dim3 pw_grid(64, 128, 2), pw_blk(32, 8);
  pack_both<<<pw_grid, pw_blk, 0, stream>>>(W0, W1, W0b, W0t, W1b, W1t);

  dim3 blk(512);
  dim3 g1(H2 / 256, Mrows / 256);   // 16 x 64
  dim3 g2(Hh / 256, Mrows / 256);   //  8 x 64

  // T1 = tanh(u_old @ W1^T + b1)                    [V7 arm]
  gemm_t1<<<g1, blk, 0, stream>>>(Ab, W1b, b1, T, Mrows, H2, Hh);
  // v_new = v_old + 0.1*(T1 @ W1)                   [V7 arm]
  gemm_vnew<<<g2, blk, 0, stream>>>(T, W1t, x + Hh, out + Hh, Ab, 0.1f,
                                    Mrows, Hh, H2);
  // T2 = tanh(v_new @ W0^T + b0)                    [V3 control]
  gemm_t2<<<g1, blk, 0, stream>>>(Ab, W0b, b0, T, Mrows, H2, Hh);
  // u_new = u_old - 0.1*(T2 @ W0)                   [V3 control]
  gemm_unew<<<g2, blk, 0, stream>>>(T, W0t, x, out, -0.1f, Mrows, Hh, H2);
}

// Round 19
// 1116.102 us; speedup vs baseline: 1.3459x; 1.3459x over previous
//
#include <hip/hip_runtime.h>
#include <hip/hip_bf16.h>
#include <stdint.h>

// InvBlock: out = concat(u_new, v_new)
//   v_mid = tanh(u_old @ W1^T + b1); v_new = v_old + 0.1 * (v_mid @ W1)
//   u_mid = tanh(v_new @ W0^T + b0); u_new = u_old - 0.1 * (u_mid @ W0)
// R19: revert to R17 uniform V3 (measured best: 1124.7us; V3 bracketed
// against 9 schedule variants). A/B: t2 = V3 without setprio (m190:
// setprio mildly harmful on lockstep GEMM); t1 = V3+prio control.

typedef __attribute__((ext_vector_type(8))) short short8;   // 8 bf16 = 4 VGPRs
typedef __attribute__((ext_vector_type(4))) float f32x4;

#define DEVINL __device__ __forceinline__

DEVINL ushort f2b(float f) {  // fp32 -> bf16 bits, RNE
  union { float f; uint32_t u; } v; v.f = f;
  uint32_t u = v.u;
  return (ushort)((u + 0x7fffu + ((u >> 16) & 1u)) >> 16);
}

DEVINL float fast_tanh(float x) {
  x = fminf(10.0f, fmaxf(-10.0f, x));
  float e = __expf(2.0f * x);
  return (e - 1.0f) * __builtin_amdgcn_rcpf(e + 1.0f);
}

DEVINL void gload16(const ushort* g, ushort* l) {
  __builtin_amdgcn_global_load_lds(
      (const __attribute__((address_space(1))) void*)g,
      (__attribute__((address_space(3))) void*)l, 16, 0, 0);
}

template<int MH, int NH>
DEVINL void mfma_quad(f32x4 (&acc)[8][4], const short8 (&a)[4][2],
                      const short8 (&b)[2][2]) {
#pragma unroll
  for (int ks = 0; ks < 2; ++ks)
#pragma unroll
    for (int mi = 0; mi < 4; ++mi)
#pragma unroll
      for (int ni = 0; ni < 2; ++ni)
        acc[MH * 4 + mi][NH * 2 + ni] = __builtin_amdgcn_mfma_f32_16x16x32_bf16(
            a[mi][ks], b[ni][ks], acc[MH * 4 + mi][NH * 2 + ni], 0, 0, 0);
}

// A: M x K bf16 row-major.  Bt: N x K bf16 row-major.
// MODE 0: Tout = bf16(tanh(acc + bias[n]))
// MODE 1: o = xres + step*acc -> outres fp32 + vbout bf16
// MODE 2: same as 1, no vbout
// V3: single-buf 64 KiB, counted vmcnt(2/6), 2-phase per K-tile.
// PRIO_ON: wrap MFMA clusters in s_setprio(1)/(0).
template<int MODE, int PRIO_ON>
DEVINL void gemm_body(const ushort* __restrict__ A, const ushort* __restrict__ Bt,
                      const float* __restrict__ bias, ushort* __restrict__ Tout,
                      const float* __restrict__ xres, float* __restrict__ outres,
                      ushort* __restrict__ vbout, float step, int M, int N, int K)
{
  __shared__ __align__(16) ushort ldsU[32768];   // 64 KiB: A 32KB | B 32KB

  const int tid  = threadIdx.x;
  const int wave = tid >> 6, lane = tid & 63;
  const int wr = wave >> 2, wc = wave & 3;       // 2 x 4 wave grid
  const int lr = lane & 15, hi = lane >> 4;

  // T1: XCD-aware block swizzle (nwg % 8 == 0 for all our shapes)
  const int GX = gridDim.x;
  const int nwg = GX * gridDim.y;
  const int lin = blockIdx.y * GX + blockIdx.x;
  const int swz = (lin & 7) * (nwg >> 3) + (lin >> 3);
  const int by = swz / GX, bx = swz - by * GX;
  const int m0 = by * 256, n0 = bx * 256;

  // ---- staging source offsets (inverse-swizzled global source, rule #21)
  const int kb_st = ((tid & 7) * 16) ^ (((tid >> 3) & 7) << 4);
  int offA[2][2], offB[2][2];   // [half][j], constant-indexed only
#pragma unroll
  for (int j = 0; j < 2; ++j) {
    const int rp = j * 64 + (tid >> 3);
#pragma unroll
    for (int h = 0; h < 2; ++h) {
      offA[h][j] = (m0 + (rp >> 6) * 128 + h * 64 + (rp & 63)) * K + (kb_st >> 1);
      offB[h][j] = (n0 + (rp >> 5) * 64 + h * 32 + (rp & 31)) * K + (kb_st >> 1);
    }
  }

#define STAGE_A(half, t) do {                                                  \
    gload16(A + (size_t)offA[half][0] + (size_t)(t) * 64,                      \
            ldsU + (half) * 8192 + tid * 8);                                   \
    gload16(A + (size_t)offA[half][1] + (size_t)(t) * 64,                      \
            ldsU + (half) * 8192 + 4096 + tid * 8);                            \
  } while (0)
#define STAGE_B(half, t) do {                                                  \
    gload16(Bt + (size_t)offB[half][0] + (size_t)(t) * 64,                     \
            ldsU + 16384 + (half) * 8192 + tid * 8);                           \
    gload16(Bt + (size_t)offB[half][1] + (size_t)(t) * 64,                     \
            ldsU + 16384 + (half) * 8192 + 4096 + tid * 8);                    \
  } while (0)

  // ---- fragment-read element offsets (ushort units; row&7 == lane&7)
  const int xm = (lane & 7) << 4;
  const int kbr0 = (hi * 16) ^ xm;          // bytes
  const int kbr1 = (64 + hi * 16) ^ xm;
  const int eA0 = (wr * 64 + lr) * 64 + (kbr0 >> 1);
  const int eA1 = (wr * 64 + lr) * 64 + (kbr1 >> 1);
  const int eB0 = (wc * 32 + lr) * 64 + (kbr0 >> 1);
  const int eB1 = (wc * 32 + lr) * 64 + (kbr1 >> 1);

#define LDSE(idx) (*(const short8*)&ldsU[idx])
#define READ_A8(dst, half) do {                                                \
    dst[0][0] = LDSE((half)*8192 +    0 + eA0);                                \
    dst[0][1] = LDSE((half)*8192 +    0 + eA1);                                \
    dst[1][0] = LDSE((half)*8192 + 1024 + eA0);                                \
    dst[1][1] = LDSE((half)*8192 + 1024 + eA1);                                \
    dst[2][0] = LDSE((half)*8192 + 2048 + eA0);                                \
    dst[2][1] = LDSE((half)*8192 + 2048 + eA1);                                \
    dst[3][0] = LDSE((half)*8192 + 3072 + eA0);                                \
    dst[3][1] = LDSE((half)*8192 + 3072 + eA1);                                \
  } while (0)
#define READ_B4(dst, half) do {                                                \
    dst[0][0] = LDSE(16384 + (half)*8192 +    0 + eB0);                        \
    dst[0][1] = LDSE(16384 + (half)*8192 +    0 + eB1);                        \
    dst[1][0] = LDSE(16384 + (half)*8192 + 1024 + eB0);                        \
    dst[1][1] = LDSE(16384 + (half)*8192 + 1024 + eB1);                        \
  } while (0)

  f32x4 acc[8][4] = {};
  short8 a0[4][2], a1[4][2], b0[2][2], b1[2][2];

#define VMW(n) asm volatile("s_waitcnt vmcnt(" #n ")" ::: "memory")
#define LGK0 asm volatile("s_waitcnt lgkmcnt(0)" ::: "memory")
#define SCB __builtin_amdgcn_sched_barrier(0)
#define BAR __builtin_amdgcn_s_barrier()
#define PRIO1 do { if (PRIO_ON) __builtin_amdgcn_s_setprio(1); } while (0)
#define PRIO0 do { if (PRIO_ON) __builtin_amdgcn_s_setprio(0); } while (0)

  const int NT = K >> 6;        // 64-wide K tiles

  // ======== V3 ========
  STAGE_A(0, 0); STAGE_A(1, 0); STAGE_B(0, 0);
  STAGE_B(1, 0);
#pragma unroll 1
  for (int t = 0; t < NT - 1; ++t) {
    VMW(2); BAR; SCB;                 // {A0,A1,B0}(t) resident block-wide
    READ_A8(a0, 0); READ_B4(b0, 0); READ_A8(a1, 1);
    LGK0; SCB;
    BAR; SCB;                         // all waves done reading the 3 regions
    STAGE_A(0, t + 1); STAGE_A(1, t + 1); STAGE_B(0, t + 1);
    PRIO1;
    mfma_quad<0, 0>(acc, a0, b0); mfma_quad<1, 0>(acc, a1, b0);
    PRIO0;
    VMW(6); BAR; SCB;                 // B1(t) resident block-wide
    READ_B4(b1, 1);
    LGK0; SCB;
    BAR; SCB;                         // all waves done reading B1
    STAGE_B(1, t + 1);
    PRIO1;
    mfma_quad<0, 1>(acc, a0, b1); mfma_quad<1, 1>(acc, a1, b1);
    PRIO0;
  }
  // Peeled last tile (no restaging)
  VMW(2); BAR; SCB;
  READ_A8(a0, 0); READ_B4(b0, 0); READ_A8(a1, 1);
  LGK0; SCB;
  PRIO1;
  mfma_quad<0, 0>(acc, a0, b0); mfma_quad<1, 0>(acc, a1, b0);
  PRIO0;
  VMW(0); BAR; SCB;
  READ_B4(b1, 1);
  LGK0; SCB;
  PRIO1;
  mfma_quad<0, 1>(acc, a0, b1); mfma_quad<1, 1>(acc, a1, b1);
  PRIO0;

  // ---- epilogue: C row = m0+wr*128+mi*16+hi*4+r, col = n0+wc*64+ni*16+lr
  const int mrow0 = m0 + wr * 128 + hi * 4;
  const int ncol0 = n0 + wc * 64 + lr;
#pragma unroll
  for (int mi = 0; mi < 8; ++mi) {
#pragma unroll
    for (int ni = 0; ni < 4; ++ni) {
      const int col = ncol0 + ni * 16;
      if (MODE == 0) {
        const float bv = bias[col];
#pragma unroll
        for (int r = 0; r < 4; ++r) {
          const int row = mrow0 + mi * 16 + r;
          Tout[(size_t)row * N + col] = f2b(fast_tanh(acc[mi][ni][r] + bv));
        }
      } else {
#pragma unroll
        for (int r = 0; r < 4; ++r) {
          const int row = mrow0 + mi * 16 + r;
          const size_t oi = (size_t)row * 4096 + col;
          const float v = fmaf(step, acc[mi][ni][r], xres[oi]);
          outres[oi] = v;
          if (MODE == 1) vbout[(size_t)row * N + col] = f2b(v);
        }
      }
    }
  }
#undef STAGE_A
#undef STAGE_B
#undef LDSE
#undef READ_A8
#undef READ_B4
#undef VMW
#undef LGK0
#undef SCB
#undef BAR
#undef PRIO1
#undef PRIO0
}

// Distinct kernel names per dispatch for unambiguous rocprof attribution.
__global__ __launch_bounds__(512, 2)
void gemm_t1(const ushort* A, const ushort* Bt, const float* bias,
             ushort* Tout, int M, int N, int K) {
  gemm_body<0, 1>(A, Bt, bias, Tout, nullptr, nullptr, nullptr, 0.f, M, N, K);
}
__global__ __launch_bounds__(512, 2)
void gemm_vnew(const ushort* A, const ushort* Bt, const float* xres,
               float* outres, ushort* vbout, float step, int M, int N, int K) {
  gemm_body<1, 1>(A, Bt, nullptr, nullptr, xres, outres, vbout, step, M, N, K);
}
__global__ __launch_bounds__(512, 2)
void gemm_t2(const ushort* A, const ushort* Bt, const float* bias,
             ushort* Tout, int M, int N, int K) {
  gemm_body<0, 0>(A, Bt, bias, Tout, nullptr, nullptr, nullptr, 0.f, M, N, K);
}
__global__ __launch_bounds__(512, 2)
void gemm_unew(const ushort* A, const ushort* Bt, const float* xres,
               float* outres, float step, int M, int N, int K) {
  gemm_body<2, 1>(A, Bt, nullptr, nullptr, xres, outres, nullptr, step, M, N, K);
}

// u_b[m, 0:2048] = bf16(x[m, 0:2048])   (x has ld 4096); short8 stores
__global__ void cast_strided_half(const float* __restrict__ x,
                                  ushort* __restrict__ dst)
{
  const int i = blockIdx.x * blockDim.x + threadIdx.x;   // [0, 16384*256)
  const int row = i >> 8;
  const int c8  = (i & 255) * 8;
  const float4 v0 = *(const float4*)&x[(size_t)row * 4096 + c8];
  const float4 v1 = *(const float4*)&x[(size_t)row * 4096 + c8 + 4];
  short8 o;
  o[0] = (short)f2b(v0.x); o[1] = (short)f2b(v0.y);
  o[2] = (short)f2b(v0.z); o[3] = (short)f2b(v0.w);
  o[4] = (short)f2b(v1.x); o[5] = (short)f2b(v1.y);
  o[6] = (short)f2b(v1.z); o[7] = (short)f2b(v1.w);
  *(short8*)&dst[(size_t)row * 2048 + c8] = o;
}

// Both weights in one launch: W (4096x2048 fp32) -> Wb (bf16) + Wt (bf16^T)
__global__ void pack_both(const float* __restrict__ W0, const float* __restrict__ W1,
                          ushort* __restrict__ W0b, ushort* __restrict__ W0t,
                          ushort* __restrict__ W1b, ushort* __restrict__ W1t)
{
  const float* W = blockIdx.z ? W1 : W0;
  ushort* Wb = blockIdx.z ? W1b : W0b;
  ushort* Wt = blockIdx.z ? W1t : W0t;
  __shared__ float tile[32][33];
  const int bx = blockIdx.x * 32;
  const int by = blockIdx.y * 32;
  const int tx = threadIdx.x, ty = threadIdx.y;   // 32x8
#pragma unroll
  for (int j = ty; j < 32; j += 8) {
    const float v = W[(size_t)(by + j) * 2048 + bx + tx];
    tile[j][tx] = v;
    Wb[(size_t)(by + j) * 2048 + bx + tx] = f2b(v);
  }
  __syncthreads();
#pragma unroll
  for (int j = ty; j < 32; j += 8) {
    Wt[(size_t)(bx + j) * 4096 + by + tx] = f2b(tile[tx][j]);
  }
}

extern "C" void kernel_launch(void* const* d_in, const int* in_sizes, int n_in,
                              void* d_out, int out_size, void* d_ws, size_t ws_size,
                              hipStream_t stream)
{
  const float* x  = (const float*)d_in[0];   // 16384 x 4096
  const float* W0 = (const float*)d_in[1];   // 4096 x 2048
  const float* b0 = (const float*)d_in[2];
  const float* W1 = (const float*)d_in[3];
  const float* b1 = (const float*)d_in[4];
  float* out = (float*)d_out;                // 16384 x 4096

  const int Mrows = 16384, H2 = 4096, Hh = 2048;

  uint8_t* ws = (uint8_t*)d_ws;
  ushort* T   = (ushort*)ws;                                   // 128 MiB
  ushort* Ab  = (ushort*)(ws + (size_t)134217728);             //  64 MiB
  ushort* W0b = (ushort*)(ws + (size_t)134217728 + 67108864);
  ushort* W0t = W0b + 8388608;
  ushort* W1b = W0t + 8388608;
  ushort* W1t = W1b + 8388608;

  cast_strided_half<<<16384, 256, 0, stream>>>(x, Ab);
  dim3 pw_grid(64, 128, 2), pw_blk(32, 8);
  pack_both<<<pw_grid, pw_blk, 0, stream>>>(W0, W1, W0b, W0t, W1b, W1t);

  dim3 blk(512);
  dim3 g1(H2 / 256, Mrows / 256);   // 16 x 64
  dim3 g2(Hh / 256, Mrows / 256);   //  8 x 64

  // T1 = tanh(u_old @ W1^T + b1)                [V3 + prio, control]
  gemm_t1<<<g1, blk, 0, stream>>>(Ab, W1b, b1, T, Mrows, H2, Hh);
  // v_new = v_old + 0.1*(T1 @ W1)               [V3 + prio]
  gemm_vnew<<<g2, blk, 0, stream>>>(T, W1t, x + Hh, out + Hh, Ab, 0.1f,
                                    Mrows, Hh, H2);
  // T2 = tanh(v_new @ W0^T + b0)                [V3 no-prio, A/B arm]
  gemm_t2<<<g1, blk, 0, stream>>>(Ab, W0b, b0, T, Mrows, H2, Hh);
  // u_new = u_old - 0.1*(T2 @ W0)               [V3 + prio]
  gemm_unew<<<g2, blk, 0, stream>>>(T, W0t, x, out, -0.1f, Mrows, Hh, H2);
}

// Round 20
// 1109.857 us; speedup vs baseline: 1.3535x; 1.0056x over previous
//
#include <hip/hip_runtime.h>
#include <hip/hip_bf16.h>
#include <stdint.h>

// InvBlock: out = concat(u_new, v_new)
//   v_mid = tanh(u_old @ W1^T + b1); v_new = v_old + 0.1 * (v_mid @ W1)
//   u_mid = tanh(v_new @ W0^T + b0); u_new = u_old - 0.1 * (u_mid @ W0)
// R20: uniform V3, NO setprio anywhere (R19 A/B: t2 no-prio improved
// total 1124.7 -> 1116.1; m190: setprio harmful on lockstep GEMM).
// V3 = single-buf 64 KiB, counted vmcnt(2/6), 2-phase per K-tile —
// bracketed best against 9 schedule variants (R1..R18).

typedef __attribute__((ext_vector_type(8))) short short8;   // 8 bf16 = 4 VGPRs
typedef __attribute__((ext_vector_type(4))) float f32x4;

#define DEVINL __device__ __forceinline__

DEVINL ushort f2b(float f) {  // fp32 -> bf16 bits, RNE
  union { float f; uint32_t u; } v; v.f = f;
  uint32_t u = v.u;
  return (ushort)((u + 0x7fffu + ((u >> 16) & 1u)) >> 16);
}

DEVINL float fast_tanh(float x) {
  x = fminf(10.0f, fmaxf(-10.0f, x));
  float e = __expf(2.0f * x);
  return (e - 1.0f) * __builtin_amdgcn_rcpf(e + 1.0f);
}

DEVINL void gload16(const ushort* g, ushort* l) {
  __builtin_amdgcn_global_load_lds(
      (const __attribute__((address_space(1))) void*)g,
      (__attribute__((address_space(3))) void*)l, 16, 0, 0);
}

template<int MH, int NH>
DEVINL void mfma_quad(f32x4 (&acc)[8][4], const short8 (&a)[4][2],
                      const short8 (&b)[2][2]) {
#pragma unroll
  for (int ks = 0; ks < 2; ++ks)
#pragma unroll
    for (int mi = 0; mi < 4; ++mi)
#pragma unroll
      for (int ni = 0; ni < 2; ++ni)
        acc[MH * 4 + mi][NH * 2 + ni] = __builtin_amdgcn_mfma_f32_16x16x32_bf16(
            a[mi][ks], b[ni][ks], acc[MH * 4 + mi][NH * 2 + ni], 0, 0, 0);
}

// A: M x K bf16 row-major.  Bt: N x K bf16 row-major.
// MODE 0: Tout = bf16(tanh(acc + bias[n]))
// MODE 1: o = xres + step*acc -> outres fp32 + vbout bf16
// MODE 2: same as 1, no vbout
template<int MODE>
DEVINL void gemm_body(const ushort* __restrict__ A, const ushort* __restrict__ Bt,
                      const float* __restrict__ bias, ushort* __restrict__ Tout,
                      const float* __restrict__ xres, float* __restrict__ outres,
                      ushort* __restrict__ vbout, float step, int M, int N, int K)
{
  __shared__ __align__(16) ushort ldsU[32768];   // 64 KiB: A 32KB | B 32KB

  const int tid  = threadIdx.x;
  const int wave = tid >> 6, lane = tid & 63;
  const int wr = wave >> 2, wc = wave & 3;       // 2 x 4 wave grid
  const int lr = lane & 15, hi = lane >> 4;

  // T1: XCD-aware block swizzle (nwg % 8 == 0 for all our shapes)
  const int GX = gridDim.x;
  const int nwg = GX * gridDim.y;
  const int lin = blockIdx.y * GX + blockIdx.x;
  const int swz = (lin & 7) * (nwg >> 3) + (lin >> 3);
  const int by = swz / GX, bx = swz - by * GX;
  const int m0 = by * 256, n0 = bx * 256;

  // ---- staging source offsets (inverse-swizzled global source, rule #21)
  const int kb_st = ((tid & 7) * 16) ^ (((tid >> 3) & 7) << 4);
  int offA[2][2], offB[2][2];   // [half][j], constant-indexed only
#pragma unroll
  for (int j = 0; j < 2; ++j) {
    const int rp = j * 64 + (tid >> 3);
#pragma unroll
    for (int h = 0; h < 2; ++h) {
      offA[h][j] = (m0 + (rp >> 6) * 128 + h * 64 + (rp & 63)) * K + (kb_st >> 1);
      offB[h][j] = (n0 + (rp >> 5) * 64 + h * 32 + (rp & 31)) * K + (kb_st >> 1);
    }
  }

#define STAGE_A(half, t) do {                                                  \
    gload16(A + (size_t)offA[half][0] + (size_t)(t) * 64,                      \
            ldsU + (half) * 8192 + tid * 8);                                   \
    gload16(A + (size_t)offA[half][1] + (size_t)(t) * 64,                      \
            ldsU + (half) * 8192 + 4096 + tid * 8);                            \
  } while (0)
#define STAGE_B(half, t) do {                                                  \
    gload16(Bt + (size_t)offB[half][0] + (size_t)(t) * 64,                     \
            ldsU + 16384 + (half) * 8192 + tid * 8);                           \
    gload16(Bt + (size_t)offB[half][1] + (size_t)(t) * 64,                     \
            ldsU + 16384 + (half) * 8192 + 4096 + tid * 8);                    \
  } while (0)

  // ---- fragment-read element offsets (ushort units; row&7 == lane&7)
  const int xm = (lane & 7) << 4;
  const int kbr0 = (hi * 16) ^ xm;          // bytes
  const int kbr1 = (64 + hi * 16) ^ xm;
  const int eA0 = (wr * 64 + lr) * 64 + (kbr0 >> 1);
  const int eA1 = (wr * 64 + lr) * 64 + (kbr1 >> 1);
  const int eB0 = (wc * 32 + lr) * 64 + (kbr0 >> 1);
  const int eB1 = (wc * 32 + lr) * 64 + (kbr1 >> 1);

#define LDSE(idx) (*(const short8*)&ldsU[idx])
#define READ_A8(dst, half) do {                                                \
    dst[0][0] = LDSE((half)*8192 +    0 + eA0);                                \
    dst[0][1] = LDSE((half)*8192 +    0 + eA1);                                \
    dst[1][0] = LDSE((half)*8192 + 1024 + eA0);                                \
    dst[1][1] = LDSE((half)*8192 + 1024 + eA1);                                \
    dst[2][0] = LDSE((half)*8192 + 2048 + eA0);                                \
    dst[2][1] = LDSE((half)*8192 + 2048 + eA1);                                \
    dst[3][0] = LDSE((half)*8192 + 3072 + eA0);                                \
    dst[3][1] = LDSE((half)*8192 + 3072 + eA1);                                \
  } while (0)
#define READ_B4(dst, half) do {                                                \
    dst[0][0] = LDSE(16384 + (half)*8192 +    0 + eB0);                        \
    dst[0][1] = LDSE(16384 + (half)*8192 +    0 + eB1);                        \
    dst[1][0] = LDSE(16384 + (half)*8192 + 1024 + eB0);                        \
    dst[1][1] = LDSE(16384 + (half)*8192 + 1024 + eB1);                        \
  } while (0)

  f32x4 acc[8][4] = {};
  short8 a0[4][2], a1[4][2], b0[2][2], b1[2][2];

#define VMW(n) asm volatile("s_waitcnt vmcnt(" #n ")" ::: "memory")
#define LGK0 asm volatile("s_waitcnt lgkmcnt(0)" ::: "memory")
#define SCB __builtin_amdgcn_sched_barrier(0)
#define BAR __builtin_amdgcn_s_barrier()

  const int NT = K >> 6;        // 64-wide K tiles

  // ======== V3 ========
  STAGE_A(0, 0); STAGE_A(1, 0); STAGE_B(0, 0);
  STAGE_B(1, 0);
#pragma unroll 1
  for (int t = 0; t < NT - 1; ++t) {
    VMW(2); BAR; SCB;                 // {A0,A1,B0}(t) resident block-wide
    READ_A8(a0, 0); READ_B4(b0, 0); READ_A8(a1, 1);
    LGK0; SCB;
    BAR; SCB;                         // all waves done reading the 3 regions
    STAGE_A(0, t + 1); STAGE_A(1, t + 1); STAGE_B(0, t + 1);
    mfma_quad<0, 0>(acc, a0, b0); mfma_quad<1, 0>(acc, a1, b0);
    VMW(6); BAR; SCB;                 // B1(t) resident block-wide
    READ_B4(b1, 1);
    LGK0; SCB;
    BAR; SCB;                         // all waves done reading B1
    STAGE_B(1, t + 1);
    mfma_quad<0, 1>(acc, a0, b1); mfma_quad<1, 1>(acc, a1, b1);
  }
  // Peeled last tile (no restaging)
  VMW(2); BAR; SCB;
  READ_A8(a0, 0); READ_B4(b0, 0); READ_A8(a1, 1);
  LGK0; SCB;
  mfma_quad<0, 0>(acc, a0, b0); mfma_quad<1, 0>(acc, a1, b0);
  VMW(0); BAR; SCB;
  READ_B4(b1, 1);
  LGK0; SCB;
  mfma_quad<0, 1>(acc, a0, b1); mfma_quad<1, 1>(acc, a1, b1);

  // ---- epilogue: C row = m0+wr*128+mi*16+hi*4+r, col = n0+wc*64+ni*16+lr
  const int mrow0 = m0 + wr * 128 + hi * 4;
  const int ncol0 = n0 + wc * 64 + lr;
#pragma unroll
  for (int mi = 0; mi < 8; ++mi) {
#pragma unroll
    for (int ni = 0; ni < 4; ++ni) {
      const int col = ncol0 + ni * 16;
      if (MODE == 0) {
        const float bv = bias[col];
#pragma unroll
        for (int r = 0; r < 4; ++r) {
          const int row = mrow0 + mi * 16 + r;
          Tout[(size_t)row * N + col] = f2b(fast_tanh(acc[mi][ni][r] + bv));
        }
      } else {
#pragma unroll
        for (int r = 0; r < 4; ++r) {
          const int row = mrow0 + mi * 16 + r;
          const size_t oi = (size_t)row * 4096 + col;
          const float v = fmaf(step, acc[mi][ni][r], xres[oi]);
          outres[oi] = v;
          if (MODE == 1) vbout[(size_t)row * N + col] = f2b(v);
        }
      }
    }
  }
#undef STAGE_A
#undef STAGE_B
#undef LDSE
#undef READ_A8
#undef READ_B4
#undef VMW
#undef LGK0
#undef SCB
#undef BAR
}

// Distinct kernel names per dispatch for unambiguous rocprof attribution.
__global__ __launch_bounds__(512, 2)
void gemm_t1(const ushort* A, const ushort* Bt, const float* bias,
             ushort* Tout, int M, int N, int K) {
  gemm_body<0>(A, Bt, bias, Tout, nullptr, nullptr, nullptr, 0.f, M, N, K);
}
__global__ __launch_bounds__(512, 2)
void gemm_vnew(const ushort* A, const ushort* Bt, const float* xres,
               float* outres, ushort* vbout, float step, int M, int N, int K) {
  gemm_body<1>(A, Bt, nullptr, nullptr, xres, outres, vbout, step, M, N, K);
}
__global__ __launch_bounds__(512, 2)
void gemm_t2(const ushort* A, const ushort* Bt, const float* bias,
             ushort* Tout, int M, int N, int K) {
  gemm_body<0>(A, Bt, bias, Tout, nullptr, nullptr, nullptr, 0.f, M, N, K);
}
__global__ __launch_bounds__(512, 2)
void gemm_unew(const ushort* A, const ushort* Bt, const float* xres,
               float* outres, float step, int M, int N, int K) {
  gemm_body<2>(A, Bt, nullptr, nullptr, xres, outres, nullptr, step, M, N, K);
}

// u_b[m, 0:2048] = bf16(x[m, 0:2048])   (x has ld 4096); short8 stores
__global__ void cast_strided_half(const float* __restrict__ x,
                                  ushort* __restrict__ dst)
{
  const int i = blockIdx.x * blockDim.x + threadIdx.x;   // [0, 16384*256)
  const int row = i >> 8;
  const int c8  = (i & 255) * 8;
  const float4 v0 = *(const float4*)&x[(size_t)row * 4096 + c8];
  const float4 v1 = *(const float4*)&x[(size_t)row * 4096 + c8 + 4];
  short8 o;
  o[0] = (short)f2b(v0.x); o[1] = (short)f2b(v0.y);
  o[2] = (short)f2b(v0.z); o[3] = (short)f2b(v0.w);
  o[4] = (short)f2b(v1.x); o[5] = (short)f2b(v1.y);
  o[6] = (short)f2b(v1.z); o[7] = (short)f2b(v1.w);
  *(short8*)&dst[(size_t)row * 2048 + c8] = o;
}

// Both weights in one launch: W (4096x2048 fp32) -> Wb (bf16) + Wt (bf16^T)
__global__ void pack_both(const float* __restrict__ W0, const float* __restrict__ W1,
                          ushort* __restrict__ W0b, ushort* __restrict__ W0t,
                          ushort* __restrict__ W1b, ushort* __restrict__ W1t)
{
  const float* W = blockIdx.z ? W1 : W0;
  ushort* Wb = blockIdx.z ? W1b : W0b;
  ushort* Wt = blockIdx.z ? W1t : W0t;
  __shared__ float tile[32][33];
  const int bx = blockIdx.x * 32;
  const int by = blockIdx.y * 32;
  const int tx = threadIdx.x, ty = threadIdx.y;   // 32x8
#pragma unroll
  for (int j = ty; j < 32; j += 8) {
    const float v = W[(size_t)(by + j) * 2048 + bx + tx];
    tile[j][tx] = v;
    Wb[(size_t)(by + j) * 2048 + bx + tx] = f2b(v);
  }
  __syncthreads();
#pragma unroll
  for (int j = ty; j < 32; j += 8) {
    Wt[(size_t)(bx + j) * 4096 + by + tx] = f2b(tile[tx][j]);
  }
}

extern "C" void kernel_launch(void* const* d_in, const int* in_sizes, int n_in,
                              void* d_out, int out_size, void* d_ws, size_t ws_size,
                              hipStream_t stream)
{
  const float* x  = (const float*)d_in[0];   // 16384 x 4096
  const float* W0 = (const float*)d_in[1];   // 4096 x 2048
  const float* b0 = (const float*)d_in[2];
  const float* W1 = (const float*)d_in[3];
  const float* b1 = (const float*)d_in[4];
  float* out = (float*)d_out;                // 16384 x 4096

  const int Mrows = 16384, H2 = 4096, Hh = 2048;

  uint8_t* ws = (uint8_t*)d_ws;
  ushort* T   = (ushort*)ws;                                   // 128 MiB
  ushort* Ab  = (ushort*)(ws + (size_t)134217728);             //  64 MiB
  ushort* W0b = (ushort*)(ws + (size_t)134217728 + 67108864);
  ushort* W0t = W0b + 8388608;
  ushort* W1b = W0t + 8388608;
  ushort* W1t = W1b + 8388608;

  cast_strided_half<<<16384, 256, 0, stream>>>(x, Ab);
  dim3 pw_grid(64, 128, 2), pw_blk(32, 8);
  pack_both<<<pw_grid, pw_blk, 0, stream>>>(W0, W1, W0b, W0t, W1b, W1t);

  dim3 blk(512);
  dim3 g1(H2 / 256, Mrows / 256);   // 16 x 64
  dim3 g2(Hh / 256, Mrows / 256);   //  8 x 64

  // T1 = tanh(u_old @ W1^T + b1)
  gemm_t1<<<g1, blk, 0, stream>>>(Ab, W1b, b1, T, Mrows, H2, Hh);
  // v_new = v_old + 0.1*(T1 @ W1)  -> out[:,2048:] fp32 + Ab bf16
  gemm_vnew<<<g2, blk, 0, stream>>>(T, W1t, x + Hh, out + Hh, Ab, 0.1f,
                                    Mrows, Hh, H2);
  // T2 = tanh(v_new @ W0^T + b0)
  gemm_t2<<<g1, blk, 0, stream>>>(Ab, W0b, b0, T, Mrows, H2, Hh);
  // u_new = u_old - 0.1*(T2 @ W0)  -> out[:,:2048] fp32
  gemm_unew<<<g2, blk, 0, stream>>>(T, W0t, x, out, -0.1f, Mrows, Hh, H2);
}

// Round 21
// 1097.359 us; speedup vs baseline: 1.3689x; 1.0114x over previous
//
#include <hip/hip_runtime.h>
#include <hip/hip_bf16.h>
#include <stdint.h>

// InvBlock: out = concat(u_new, v_new)
//   v_mid = tanh(u_old @ W1^T + b1); v_new = v_old + 0.1 * (v_mid @ W1)
//   u_mid = tanh(v_new @ W0^T + b0); u_new = u_old - 0.1 * (u_mid @ W0)
// R21: R20 (uniform V3, no setprio — 1109.9us) + epilogue store-order fix:
// mi->r->ni (ni innermost) so the 4 ni-stores of one row issue adjacently
// and write-combine into full sectors (MODE0 WRITE 228MB vs 128 ideal all
// session; 16-lane 32B runs were interleaved across rows).

typedef __attribute__((ext_vector_type(8))) short short8;   // 8 bf16 = 4 VGPRs
typedef __attribute__((ext_vector_type(4))) float f32x4;

#define DEVINL __device__ __forceinline__

DEVINL ushort f2b(float f) {  // fp32 -> bf16 bits, RNE
  union { float f; uint32_t u; } v; v.f = f;
  uint32_t u = v.u;
  return (ushort)((u + 0x7fffu + ((u >> 16) & 1u)) >> 16);
}

DEVINL float fast_tanh(float x) {
  x = fminf(10.0f, fmaxf(-10.0f, x));
  float e = __expf(2.0f * x);
  return (e - 1.0f) * __builtin_amdgcn_rcpf(e + 1.0f);
}

DEVINL void gload16(const ushort* g, ushort* l) {
  __builtin_amdgcn_global_load_lds(
      (const __attribute__((address_space(1))) void*)g,
      (__attribute__((address_space(3))) void*)l, 16, 0, 0);
}

template<int MH, int NH>
DEVINL void mfma_quad(f32x4 (&acc)[8][4], const short8 (&a)[4][2],
                      const short8 (&b)[2][2]) {
#pragma unroll
  for (int ks = 0; ks < 2; ++ks)
#pragma unroll
    for (int mi = 0; mi < 4; ++mi)
#pragma unroll
      for (int ni = 0; ni < 2; ++ni)
        acc[MH * 4 + mi][NH * 2 + ni] = __builtin_amdgcn_mfma_f32_16x16x32_bf16(
            a[mi][ks], b[ni][ks], acc[MH * 4 + mi][NH * 2 + ni], 0, 0, 0);
}

// A: M x K bf16 row-major.  Bt: N x K bf16 row-major.
// MODE 0: Tout = bf16(tanh(acc + bias[n]))
// MODE 1: o = xres + step*acc -> outres fp32 + vbout bf16
// MODE 2: same as 1, no vbout
template<int MODE>
DEVINL void gemm_body(const ushort* __restrict__ A, const ushort* __restrict__ Bt,
                      const float* __restrict__ bias, ushort* __restrict__ Tout,
                      const float* __restrict__ xres, float* __restrict__ outres,
                      ushort* __restrict__ vbout, float step, int M, int N, int K)
{
  __shared__ __align__(16) ushort ldsU[32768];   // 64 KiB: A 32KB | B 32KB

  const int tid  = threadIdx.x;
  const int wave = tid >> 6, lane = tid & 63;
  const int wr = wave >> 2, wc = wave & 3;       // 2 x 4 wave grid
  const int lr = lane & 15, hi = lane >> 4;

  // T1: XCD-aware block swizzle (nwg % 8 == 0 for all our shapes)
  const int GX = gridDim.x;
  const int nwg = GX * gridDim.y;
  const int lin = blockIdx.y * GX + blockIdx.x;
  const int swz = (lin & 7) * (nwg >> 3) + (lin >> 3);
  const int by = swz / GX, bx = swz - by * GX;
  const int m0 = by * 256, n0 = bx * 256;

  // ---- staging source offsets (inverse-swizzled global source, rule #21)
  const int kb_st = ((tid & 7) * 16) ^ (((tid >> 3) & 7) << 4);
  int offA[2][2], offB[2][2];   // [half][j], constant-indexed only
#pragma unroll
  for (int j = 0; j < 2; ++j) {
    const int rp = j * 64 + (tid >> 3);
#pragma unroll
    for (int h = 0; h < 2; ++h) {
      offA[h][j] = (m0 + (rp >> 6) * 128 + h * 64 + (rp & 63)) * K + (kb_st >> 1);
      offB[h][j] = (n0 + (rp >> 5) * 64 + h * 32 + (rp & 31)) * K + (kb_st >> 1);
    }
  }

#define STAGE_A(half, t) do {                                                  \
    gload16(A + (size_t)offA[half][0] + (size_t)(t) * 64,                      \
            ldsU + (half) * 8192 + tid * 8);                                   \
    gload16(A + (size_t)offA[half][1] + (size_t)(t) * 64,                      \
            ldsU + (half) * 8192 + 4096 + tid * 8);                            \
  } while (0)
#define STAGE_B(half, t) do {                                                  \
    gload16(Bt + (size_t)offB[half][0] + (size_t)(t) * 64,                     \
            ldsU + 16384 + (half) * 8192 + tid * 8);                           \
    gload16(Bt + (size_t)offB[half][1] + (size_t)(t) * 64,                     \
            ldsU + 16384 + (half) * 8192 + 4096 + tid * 8);                    \
  } while (0)

  // ---- fragment-read element offsets (ushort units; row&7 == lane&7)
  const int xm = (lane & 7) << 4;
  const int kbr0 = (hi * 16) ^ xm;          // bytes
  const int kbr1 = (64 + hi * 16) ^ xm;
  const int eA0 = (wr * 64 + lr) * 64 + (kbr0 >> 1);
  const int eA1 = (wr * 64 + lr) * 64 + (kbr1 >> 1);
  const int eB0 = (wc * 32 + lr) * 64 + (kbr0 >> 1);
  const int eB1 = (wc * 32 + lr) * 64 + (kbr1 >> 1);

#define LDSE(idx) (*(const short8*)&ldsU[idx])
#define READ_A8(dst, half) do {                                                \
    dst[0][0] = LDSE((half)*8192 +    0 + eA0);                                \
    dst[0][1] = LDSE((half)*8192 +    0 + eA1);                                \
    dst[1][0] = LDSE((half)*8192 + 1024 + eA0);                                \
    dst[1][1] = LDSE((half)*8192 + 1024 + eA1);                                \
    dst[2][0] = LDSE((half)*8192 + 2048 + eA0);                                \
    dst[2][1] = LDSE((half)*8192 + 2048 + eA1);                                \
    dst[3][0] = LDSE((half)*8192 + 3072 + eA0);                                \
    dst[3][1] = LDSE((half)*8192 + 3072 + eA1);                                \
  } while (0)
#define READ_B4(dst, half) do {                                                \
    dst[0][0] = LDSE(16384 + (half)*8192 +    0 + eB0);                        \
    dst[0][1] = LDSE(16384 + (half)*8192 +    0 + eB1);                        \
    dst[1][0] = LDSE(16384 + (half)*8192 + 1024 + eB0);                        \
    dst[1][1] = LDSE(16384 + (half)*8192 + 1024 + eB1);                        \
  } while (0)

  f32x4 acc[8][4] = {};
  short8 a0[4][2], a1[4][2], b0[2][2], b1[2][2];

#define VMW(n) asm volatile("s_waitcnt vmcnt(" #n ")" ::: "memory")
#define LGK0 asm volatile("s_waitcnt lgkmcnt(0)" ::: "memory")
#define SCB __builtin_amdgcn_sched_barrier(0)
#define BAR __builtin_amdgcn_s_barrier()

  const int NT = K >> 6;        // 64-wide K tiles

  // ======== V3 ========
  STAGE_A(0, 0); STAGE_A(1, 0); STAGE_B(0, 0);
  STAGE_B(1, 0);
#pragma unroll 1
  for (int t = 0; t < NT - 1; ++t) {
    VMW(2); BAR; SCB;                 // {A0,A1,B0}(t) resident block-wide
    READ_A8(a0, 0); READ_B4(b0, 0); READ_A8(a1, 1);
    LGK0; SCB;
    BAR; SCB;                         // all waves done reading the 3 regions
    STAGE_A(0, t + 1); STAGE_A(1, t + 1); STAGE_B(0, t + 1);
    mfma_quad<0, 0>(acc, a0, b0); mfma_quad<1, 0>(acc, a1, b0);
    VMW(6); BAR; SCB;                 // B1(t) resident block-wide
    READ_B4(b1, 1);
    LGK0; SCB;
    BAR; SCB;                         // all waves done reading B1
    STAGE_B(1, t + 1);
    mfma_quad<0, 1>(acc, a0, b1); mfma_quad<1, 1>(acc, a1, b1);
  }
  // Peeled last tile (no restaging)
  VMW(2); BAR; SCB;
  READ_A8(a0, 0); READ_B4(b0, 0); READ_A8(a1, 1);
  LGK0; SCB;
  mfma_quad<0, 0>(acc, a0, b0); mfma_quad<1, 0>(acc, a1, b0);
  VMW(0); BAR; SCB;
  READ_B4(b1, 1);
  LGK0; SCB;
  mfma_quad<0, 1>(acc, a0, b1); mfma_quad<1, 1>(acc, a1, b1);

  // ---- epilogue: C row = m0+wr*128+mi*16+hi*4+r, col = n0+wc*64+ni*16+lr
  // Store order mi->r->ni: the 4 ni-stores of one row issue adjacently ->
  // lanes 0..15 cover a contiguous 128B (bf16) / 256B (fp32) span.
  const int mrow0 = m0 + wr * 128 + hi * 4;
  const int ncol0 = n0 + wc * 64 + lr;
  if (MODE == 0) {
    float bv[4];
#pragma unroll
    for (int ni = 0; ni < 4; ++ni) bv[ni] = bias[ncol0 + ni * 16];
#pragma unroll
    for (int mi = 0; mi < 8; ++mi) {
#pragma unroll
      for (int r = 0; r < 4; ++r) {
        const int row = mrow0 + mi * 16 + r;
#pragma unroll
        for (int ni = 0; ni < 4; ++ni)
          Tout[(size_t)row * N + ncol0 + ni * 16] =
              f2b(fast_tanh(acc[mi][ni][r] + bv[ni]));
      }
    }
  } else {
#pragma unroll
    for (int mi = 0; mi < 8; ++mi) {
#pragma unroll
      for (int r = 0; r < 4; ++r) {
        const int row = mrow0 + mi * 16 + r;
#pragma unroll
        for (int ni = 0; ni < 4; ++ni) {
          const size_t oi = (size_t)row * 4096 + ncol0 + ni * 16;
          const float v = fmaf(step, acc[mi][ni][r], xres[oi]);
          outres[oi] = v;
          if (MODE == 1) vbout[(size_t)row * N + ncol0 + ni * 16] = f2b(v);
        }
      }
    }
  }
#undef STAGE_A
#undef STAGE_B
#undef LDSE
#undef READ_A8
#undef READ_B4
#undef VMW
#undef LGK0
#undef SCB
#undef BAR
}

// Distinct kernel names per dispatch for unambiguous rocprof attribution.
__global__ __launch_bounds__(512, 2)
void gemm_t1(const ushort* A, const ushort* Bt, const float* bias,
             ushort* Tout, int M, int N, int K) {
  gemm_body<0>(A, Bt, bias, Tout, nullptr, nullptr, nullptr, 0.f, M, N, K);
}
__global__ __launch_bounds__(512, 2)
void gemm_vnew(const ushort* A, const ushort* Bt, const float* xres,
               float* outres, ushort* vbout, float step, int M, int N, int K) {
  gemm_body<1>(A, Bt, nullptr, nullptr, xres, outres, vbout, step, M, N, K);
}
__global__ __launch_bounds__(512, 2)
void gemm_t2(const ushort* A, const ushort* Bt, const float* bias,
             ushort* Tout, int M, int N, int K) {
  gemm_body<0>(A, Bt, bias, Tout, nullptr, nullptr, nullptr, 0.f, M, N, K);
}
__global__ __launch_bounds__(512, 2)
void gemm_unew(const ushort* A, const ushort* Bt, const float* xres,
               float* outres, float step, int M, int N, int K) {
  gemm_body<2>(A, Bt, nullptr, nullptr, xres, outres, nullptr, step, M, N, K);
}

// u_b[m, 0:2048] = bf16(x[m, 0:2048])   (x has ld 4096); short8 stores
__global__ void cast_strided_half(const float* __restrict__ x,
                                  ushort* __restrict__ dst)
{
  const int i = blockIdx.x * blockDim.x + threadIdx.x;   // [0, 16384*256)
  const int row = i >> 8;
  const int c8  = (i & 255) * 8;
  const float4 v0 = *(const float4*)&x[(size_t)row * 4096 + c8];
  const float4 v1 = *(const float4*)&x[(size_t)row * 4096 + c8 + 4];
  short8 o;
  o[0] = (short)f2b(v0.x); o[1] = (short)f2b(v0.y);
  o[2] = (short)f2b(v0.z); o[3] = (short)f2b(v0.w);
  o[4] = (short)f2b(v1.x); o[5] = (short)f2b(v1.y);
  o[6] = (short)f2b(v1.z); o[7] = (short)f2b(v1.w);
  *(short8*)&dst[(size_t)row * 2048 + c8] = o;
}

// Both weights in one launch: W (4096x2048 fp32) -> Wb (bf16) + Wt (bf16^T)
__global__ void pack_both(const float* __restrict__ W0, const float* __restrict__ W1,
                          ushort* __restrict__ W0b, ushort* __restrict__ W0t,
                          ushort* __restrict__ W1b, ushort* __restrict__ W1t)
{
  const float* W = blockIdx.z ? W1 : W0;
  ushort* Wb = blockIdx.z ? W1b : W0b;
  ushort* Wt = blockIdx.z ? W1t : W0t;
  __shared__ float tile[32][33];
  const int bx = blockIdx.x * 32;
  const int by = blockIdx.y * 32;
  const int tx = threadIdx.x, ty = threadIdx.y;   // 32x8
#pragma unroll
  for (int j = ty; j < 32; j += 8) {
    const float v = W[(size_t)(by + j) * 2048 + bx + tx];
    tile[j][tx] = v;
    Wb[(size_t)(by + j) * 2048 + bx + tx] = f2b(v);
  }
  __syncthreads();
#pragma unroll
  for (int j = ty; j < 32; j += 8) {
    Wt[(size_t)(bx + j) * 4096 + by + tx] = f2b(tile[tx][j]);
  }
}

extern "C" void kernel_launch(void* const* d_in, const int* in_sizes, int n_in,
                              void* d_out, int out_size, void* d_ws, size_t ws_size,
                              hipStream_t stream)
{
  const float* x  = (const float*)d_in[0];   // 16384 x 4096
  const float* W0 = (const float*)d_in[1];   // 4096 x 2048
  const float* b0 = (const float*)d_in[2];
  const float* W1 = (const float*)d_in[3];
  const float* b1 = (const float*)d_in[4];
  float* out = (float*)d_out;                // 16384 x 4096

  const int Mrows = 16384, H2 = 4096, Hh = 2048;

  uint8_t* ws = (uint8_t*)d_ws;
  ushort* T   = (ushort*)ws;                                   // 128 MiB
  ushort* Ab  = (ushort*)(ws + (size_t)134217728);             //  64 MiB
  ushort* W0b = (ushort*)(ws + (size_t)134217728 + 67108864);
  ushort* W0t = W0b + 8388608;
  ushort* W1b = W0t + 8388608;
  ushort* W1t = W1b + 8388608;

  cast_strided_half<<<16384, 256, 0, stream>>>(x, Ab);
  dim3 pw_grid(64, 128, 2), pw_blk(32, 8);
  pack_both<<<pw_grid, pw_blk, 0, stream>>>(W0, W1, W0b, W0t, W1b, W1t);

  dim3 blk(512);
  dim3 g1(H2 / 256, Mrows / 256);   // 16 x 64
  dim3 g2(Hh / 256, Mrows / 256);   //  8 x 64

  // T1 = tanh(u_old @ W1^T + b1)
  gemm_t1<<<g1, blk, 0, stream>>>(Ab, W1b, b1, T, Mrows, H2, Hh);
  // v_new = v_old + 0.1*(T1 @ W1)  -> out[:,2048:] fp32 + Ab bf16
  gemm_vnew<<<g2, blk, 0, stream>>>(T, W1t, x + Hh, out + Hh, Ab, 0.1f,
                                    Mrows, Hh, H2);
  // T2 = tanh(v_new @ W0^T + b0)
  gemm_t2<<<g1, blk, 0, stream>>>(Ab, W0b, b0, T, Mrows, H2, Hh);
  // u_new = u_old - 0.1*(T2 @ W0)  -> out[:,:2048] fp32
  gemm_unew<<<g2, blk, 0, stream>>>(T, W0t, x, out, -0.1f, Mrows, Hh, H2);
}

// Round 22
// 1085.179 us; speedup vs baseline: 1.3843x; 1.0112x over previous
//
#include <hip/hip_runtime.h>
#include <hip/hip_bf16.h>
#include <stdint.h>

// InvBlock: out = concat(u_new, v_new)
//   v_mid = tanh(u_old @ W1^T + b1); v_new = v_old + 0.1 * (v_mid @ W1)
//   u_mid = tanh(v_new @ W0^T + b0); u_new = u_old - 0.1 * (u_mid @ W0)
// R22: R21 (1097.4us) + A/B on L2-locality block ordering: t1 = 4x4
// supertile interior within XCD chunks (per-16-block working set 19MB ->
// 8MB, more VMW-stall loads served from L2 vs L3); t2 = R21 swizzle
// control (same shape+MODE). vnew/unew unchanged.

typedef __attribute__((ext_vector_type(8))) short short8;   // 8 bf16 = 4 VGPRs
typedef __attribute__((ext_vector_type(4))) float f32x4;

#define DEVINL __device__ __forceinline__

DEVINL ushort f2b(float f) {  // fp32 -> bf16 bits, RNE
  union { float f; uint32_t u; } v; v.f = f;
  uint32_t u = v.u;
  return (ushort)((u + 0x7fffu + ((u >> 16) & 1u)) >> 16);
}

DEVINL float fast_tanh(float x) {
  x = fminf(10.0f, fmaxf(-10.0f, x));
  float e = __expf(2.0f * x);
  return (e - 1.0f) * __builtin_amdgcn_rcpf(e + 1.0f);
}

DEVINL void gload16(const ushort* g, ushort* l) {
  __builtin_amdgcn_global_load_lds(
      (const __attribute__((address_space(1))) void*)g,
      (__attribute__((address_space(3))) void*)l, 16, 0, 0);
}

template<int MH, int NH>
DEVINL void mfma_quad(f32x4 (&acc)[8][4], const short8 (&a)[4][2],
                      const short8 (&b)[2][2]) {
#pragma unroll
  for (int ks = 0; ks < 2; ++ks)
#pragma unroll
    for (int mi = 0; mi < 4; ++mi)
#pragma unroll
      for (int ni = 0; ni < 2; ++ni)
        acc[MH * 4 + mi][NH * 2 + ni] = __builtin_amdgcn_mfma_f32_16x16x32_bf16(
            a[mi][ks], b[ni][ks], acc[MH * 4 + mi][NH * 2 + ni], 0, 0, 0);
}

// A: M x K bf16 row-major.  Bt: N x K bf16 row-major.
// MODE 0: Tout = bf16(tanh(acc + bias[n]))
// MODE 1: o = xres + step*acc -> outres fp32 + vbout bf16
// MODE 2: same as 1, no vbout
// SUPER: 0 = R21 XCD swizzle; 1 = XCD chunks + 4x4 supertile interior.
template<int MODE, int SUPER>
DEVINL void gemm_body(const ushort* __restrict__ A, const ushort* __restrict__ Bt,
                      const float* __restrict__ bias, ushort* __restrict__ Tout,
                      const float* __restrict__ xres, float* __restrict__ outres,
                      ushort* __restrict__ vbout, float step, int M, int N, int K)
{
  __shared__ __align__(16) ushort ldsU[32768];   // 64 KiB: A 32KB | B 32KB

  const int tid  = threadIdx.x;
  const int wave = tid >> 6, lane = tid & 63;
  const int wr = wave >> 2, wc = wave & 3;       // 2 x 4 wave grid
  const int lr = lane & 15, hi = lane >> 4;

  // T1: XCD-aware block swizzle (nwg % 8 == 0; GX%4==0, GY%4==0 for SUPER)
  const int GX = gridDim.x;
  const int nwg = GX * gridDim.y;
  const int lin = blockIdx.y * GX + blockIdx.x;
  const int swz = (lin & 7) * (nwg >> 3) + (lin >> 3);
  int bx, by;
  if (SUPER) {
    const int st = swz >> 4, wi = swz & 15;      // 4x4 supertile interior
    const int nsx = GX >> 2;
    bx = (st % nsx) * 4 + (wi & 3);
    by = (st / nsx) * 4 + (wi >> 2);
  } else {
    by = swz / GX; bx = swz - by * GX;
  }
  const int m0 = by * 256, n0 = bx * 256;

  // ---- staging source offsets (inverse-swizzled global source, rule #21)
  const int kb_st = ((tid & 7) * 16) ^ (((tid >> 3) & 7) << 4);
  int offA[2][2], offB[2][2];   // [half][j], constant-indexed only
#pragma unroll
  for (int j = 0; j < 2; ++j) {
    const int rp = j * 64 + (tid >> 3);
#pragma unroll
    for (int h = 0; h < 2; ++h) {
      offA[h][j] = (m0 + (rp >> 6) * 128 + h * 64 + (rp & 63)) * K + (kb_st >> 1);
      offB[h][j] = (n0 + (rp >> 5) * 64 + h * 32 + (rp & 31)) * K + (kb_st >> 1);
    }
  }

#define STAGE_A(half, t) do {                                                  \
    gload16(A + (size_t)offA[half][0] + (size_t)(t) * 64,                      \
            ldsU + (half) * 8192 + tid * 8);                                   \
    gload16(A + (size_t)offA[half][1] + (size_t)(t) * 64,                      \
            ldsU + (half) * 8192 + 4096 + tid * 8);                            \
  } while (0)
#define STAGE_B(half, t) do {                                                  \
    gload16(Bt + (size_t)offB[half][0] + (size_t)(t) * 64,                     \
            ldsU + 16384 + (half) * 8192 + tid * 8);                           \
    gload16(Bt + (size_t)offB[half][1] + (size_t)(t) * 64,                     \
            ldsU + 16384 + (half) * 8192 + 4096 + tid * 8);                    \
  } while (0)

  // ---- fragment-read element offsets (ushort units; row&7 == lane&7)
  const int xm = (lane & 7) << 4;
  const int kbr0 = (hi * 16) ^ xm;          // bytes
  const int kbr1 = (64 + hi * 16) ^ xm;
  const int eA0 = (wr * 64 + lr) * 64 + (kbr0 >> 1);
  const int eA1 = (wr * 64 + lr) * 64 + (kbr1 >> 1);
  const int eB0 = (wc * 32 + lr) * 64 + (kbr0 >> 1);
  const int eB1 = (wc * 32 + lr) * 64 + (kbr1 >> 1);

#define LDSE(idx) (*(const short8*)&ldsU[idx])
#define READ_A8(dst, half) do {                                                \
    dst[0][0] = LDSE((half)*8192 +    0 + eA0);                                \
    dst[0][1] = LDSE((half)*8192 +    0 + eA1);                                \
    dst[1][0] = LDSE((half)*8192 + 1024 + eA0);                                \
    dst[1][1] = LDSE((half)*8192 + 1024 + eA1);                                \
    dst[2][0] = LDSE((half)*8192 + 2048 + eA0);                                \
    dst[2][1] = LDSE((half)*8192 + 2048 + eA1);                                \
    dst[3][0] = LDSE((half)*8192 + 3072 + eA0);                                \
    dst[3][1] = LDSE((half)*8192 + 3072 + eA1);                                \
  } while (0)
#define READ_B4(dst, half) do {                                                \
    dst[0][0] = LDSE(16384 + (half)*8192 +    0 + eB0);                        \
    dst[0][1] = LDSE(16384 + (half)*8192 +    0 + eB1);                        \
    dst[1][0] = LDSE(16384 + (half)*8192 + 1024 + eB0);                        \
    dst[1][1] = LDSE(16384 + (half)*8192 + 1024 + eB1);                        \
  } while (0)

  f32x4 acc[8][4] = {};
  short8 a0[4][2], a1[4][2], b0[2][2], b1[2][2];

#define VMW(n) asm volatile("s_waitcnt vmcnt(" #n ")" ::: "memory")
#define LGK0 asm volatile("s_waitcnt lgkmcnt(0)" ::: "memory")
#define SCB __builtin_amdgcn_sched_barrier(0)
#define BAR __builtin_amdgcn_s_barrier()

  const int NT = K >> 6;        // 64-wide K tiles

  // ======== V3 ========
  STAGE_A(0, 0); STAGE_A(1, 0); STAGE_B(0, 0);
  STAGE_B(1, 0);
#pragma unroll 1
  for (int t = 0; t < NT - 1; ++t) {
    VMW(2); BAR; SCB;                 // {A0,A1,B0}(t) resident block-wide
    READ_A8(a0, 0); READ_B4(b0, 0); READ_A8(a1, 1);
    LGK0; SCB;
    BAR; SCB;                         // all waves done reading the 3 regions
    STAGE_A(0, t + 1); STAGE_A(1, t + 1); STAGE_B(0, t + 1);
    mfma_quad<0, 0>(acc, a0, b0); mfma_quad<1, 0>(acc, a1, b0);
    VMW(6); BAR; SCB;                 // B1(t) resident block-wide
    READ_B4(b1, 1);
    LGK0; SCB;
    BAR; SCB;                         // all waves done reading B1
    STAGE_B(1, t + 1);
    mfma_quad<0, 1>(acc, a0, b1); mfma_quad<1, 1>(acc, a1, b1);
  }
  // Peeled last tile (no restaging)
  VMW(2); BAR; SCB;
  READ_A8(a0, 0); READ_B4(b0, 0); READ_A8(a1, 1);
  LGK0; SCB;
  mfma_quad<0, 0>(acc, a0, b0); mfma_quad<1, 0>(acc, a1, b0);
  VMW(0); BAR; SCB;
  READ_B4(b1, 1);
  LGK0; SCB;
  mfma_quad<0, 1>(acc, a0, b1); mfma_quad<1, 1>(acc, a1, b1);

  // ---- epilogue: C row = m0+wr*128+mi*16+hi*4+r, col = n0+wc*64+ni*16+lr
  // Store order mi->r->ni (R21): 4 ni-stores of one row issue adjacently.
  const int mrow0 = m0 + wr * 128 + hi * 4;
  const int ncol0 = n0 + wc * 64 + lr;
  if (MODE == 0) {
    float bv[4];
#pragma unroll
    for (int ni = 0; ni < 4; ++ni) bv[ni] = bias[ncol0 + ni * 16];
#pragma unroll
    for (int mi = 0; mi < 8; ++mi) {
#pragma unroll
      for (int r = 0; r < 4; ++r) {
        const int row = mrow0 + mi * 16 + r;
#pragma unroll
        for (int ni = 0; ni < 4; ++ni)
          Tout[(size_t)row * N + ncol0 + ni * 16] =
              f2b(fast_tanh(acc[mi][ni][r] + bv[ni]));
      }
    }
  } else {
#pragma unroll
    for (int mi = 0; mi < 8; ++mi) {
#pragma unroll
      for (int r = 0; r < 4; ++r) {
        const int row = mrow0 + mi * 16 + r;
#pragma unroll
        for (int ni = 0; ni < 4; ++ni) {
          const size_t oi = (size_t)row * 4096 + ncol0 + ni * 16;
          const float v = fmaf(step, acc[mi][ni][r], xres[oi]);
          outres[oi] = v;
          if (MODE == 1) vbout[(size_t)row * N + ncol0 + ni * 16] = f2b(v);
        }
      }
    }
  }
#undef STAGE_A
#undef STAGE_B
#undef LDSE
#undef READ_A8
#undef READ_B4
#undef VMW
#undef LGK0
#undef SCB
#undef BAR
}

// Distinct kernel names per dispatch for unambiguous rocprof attribution.
__global__ __launch_bounds__(512, 2)
void gemm_t1(const ushort* A, const ushort* Bt, const float* bias,
             ushort* Tout, int M, int N, int K) {
  gemm_body<0, 1>(A, Bt, bias, Tout, nullptr, nullptr, nullptr, 0.f, M, N, K);
}
__global__ __launch_bounds__(512, 2)
void gemm_vnew(const ushort* A, const ushort* Bt, const float* xres,
               float* outres, ushort* vbout, float step, int M, int N, int K) {
  gemm_body<1, 0>(A, Bt, nullptr, nullptr, xres, outres, vbout, step, M, N, K);
}
__global__ __launch_bounds__(512, 2)
void gemm_t2(const ushort* A, const ushort* Bt, const float* bias,
             ushort* Tout, int M, int N, int K) {
  gemm_body<0, 0>(A, Bt, bias, Tout, nullptr, nullptr, nullptr, 0.f, M, N, K);
}
__global__ __launch_bounds__(512, 2)
void gemm_unew(const ushort* A, const ushort* Bt, const float* xres,
               float* outres, float step, int M, int N, int K) {
  gemm_body<2, 0>(A, Bt, nullptr, nullptr, xres, outres, nullptr, step, M, N, K);
}

// u_b[m, 0:2048] = bf16(x[m, 0:2048])   (x has ld 4096); short8 stores
__global__ void cast_strided_half(const float* __restrict__ x,
                                  ushort* __restrict__ dst)
{
  const int i = blockIdx.x * blockDim.x + threadIdx.x;   // [0, 16384*256)
  const int row = i >> 8;
  const int c8  = (i & 255) * 8;
  const float4 v0 = *(const float4*)&x[(size_t)row * 4096 + c8];
  const float4 v1 = *(const float4*)&x[(size_t)row * 4096 + c8 + 4];
  short8 o;
  o[0] = (short)f2b(v0.x); o[1] = (short)f2b(v0.y);
  o[2] = (short)f2b(v0.z); o[3] = (short)f2b(v0.w);
  o[4] = (short)f2b(v1.x); o[5] = (short)f2b(v1.y);
  o[6] = (short)f2b(v1.z); o[7] = (short)f2b(v1.w);
  *(short8*)&dst[(size_t)row * 2048 + c8] = o;
}

// Both weights in one launch: W (4096x2048 fp32) -> Wb (bf16) + Wt (bf16^T)
__global__ void pack_both(const float* __restrict__ W0, const float* __restrict__ W1,
                          ushort* __restrict__ W0b, ushort* __restrict__ W0t,
                          ushort* __restrict__ W1b, ushort* __restrict__ W1t)
{
  const float* W = blockIdx.z ? W1 : W0;
  ushort* Wb = blockIdx.z ? W1b : W0b;
  ushort* Wt = blockIdx.z ? W1t : W0t;
  __shared__ float tile[32][33];
  const int bx = blockIdx.x * 32;
  const int by = blockIdx.y * 32;
  const int tx = threadIdx.x, ty = threadIdx.y;   // 32x8
#pragma unroll
  for (int j = ty; j < 32; j += 8) {
    const float v = W[(size_t)(by + j) * 2048 + bx + tx];
    tile[j][tx] = v;
    Wb[(size_t)(by + j) * 2048 + bx + tx] = f2b(v);
  }
  __syncthreads();
#pragma unroll
  for (int j = ty; j < 32; j += 8) {
    Wt[(size_t)(bx + j) * 4096 + by + tx] = f2b(tile[tx][j]);
  }
}

extern "C" void kernel_launch(void* const* d_in, const int* in_sizes, int n_in,
                              void* d_out, int out_size, void* d_ws, size_t ws_size,
                              hipStream_t stream)
{
  const float* x  = (const float*)d_in[0];   // 16384 x 4096
  const float* W0 = (const float*)d_in[1];   // 4096 x 2048
  const float* b0 = (const float*)d_in[2];
  const float* W1 = (const float*)d_in[3];
  const float* b1 = (const float*)d_in[4];
  float* out = (float*)d_out;                // 16384 x 4096

  const int Mrows = 16384, H2 = 4096, Hh = 2048;

  uint8_t* ws = (uint8_t*)d_ws;
  ushort* T   = (ushort*)ws;                                   // 128 MiB
  ushort* Ab  = (ushort*)(ws + (size_t)134217728);             //  64 MiB
  ushort* W0b = (ushort*)(ws + (size_t)134217728 + 67108864);
  ushort* W0t = W0b + 8388608;
  ushort* W1b = W0t + 8388608;
  ushort* W1t = W1b + 8388608;

  cast_strided_half<<<16384, 256, 0, stream>>>(x, Ab);
  dim3 pw_grid(64, 128, 2), pw_blk(32, 8);
  pack_both<<<pw_grid, pw_blk, 0, stream>>>(W0, W1, W0b, W0t, W1b, W1t);

  dim3 blk(512);
  dim3 g1(H2 / 256, Mrows / 256);   // 16 x 64
  dim3 g2(Hh / 256, Mrows / 256);   //  8 x 64

  // T1 = tanh(u_old @ W1^T + b1)                [supertile arm]
  gemm_t1<<<g1, blk, 0, stream>>>(Ab, W1b, b1, T, Mrows, H2, Hh);
  // v_new = v_old + 0.1*(T1 @ W1)               [control]
  gemm_vnew<<<g2, blk, 0, stream>>>(T, W1t, x + Hh, out + Hh, Ab, 0.1f,
                                    Mrows, Hh, H2);
  // T2 = tanh(v_new @ W0^T + b0)                [control, same shape as t1]
  gemm_t2<<<g1, blk, 0, stream>>>(Ab, W0b, b0, T, Mrows, H2, Hh);
  // u_new = u_old - 0.1*(T2 @ W0)               [control]
  gemm_unew<<<g2, blk, 0, stream>>>(T, W0t, x, out, -0.1f, Mrows, Hh, H2);
}